// Round 1
// baseline (3068.288 us; speedup 1.0000x reference)
//
#include <hip/hip_runtime.h>
#include <cstdint>
#include <cstddef>

#define B_  2
#define S_  2048
#define D_  2560
#define H_  32
#define HD_ 80

typedef __attribute__((ext_vector_type(8))) short  short8;
typedef __attribute__((ext_vector_type(4))) float  floatx4;

__device__ __forceinline__ float b2f(unsigned short u) {
  union { unsigned int i; float f; } x; x.i = ((unsigned int)u) << 16; return x.f;
}
__device__ __forceinline__ unsigned short f2bf(float f) {
  union { float f; unsigned int i; } x; x.f = f;
  unsigned int u = x.i;
  return (unsigned short)((u + 0x7fffu + ((u >> 16) & 1u)) >> 16);
}

// fp32 -> bf16 elementwise, 4 elems/thread (all sizes divisible by 4)
__global__ void cvt_kernel(const float* __restrict__ in, unsigned short* __restrict__ out, int n4) {
  int i = blockIdx.x * 256 + threadIdx.x;
  if (i >= n4) return;
  const float4 v = ((const float4*)in)[i];
  ushort4 r;
  r.x = f2bf(v.x); r.y = f2bf(v.y); r.z = f2bf(v.z); r.w = f2bf(v.w);
  ((ushort4*)out)[i] = r;
}

#define GLOAD_LDS16(g, l)                                                      \
  __builtin_amdgcn_global_load_lds(                                            \
      (const __attribute__((address_space(1))) void*)(g),                      \
      (__attribute__((address_space(3))) void*)(l), 16, 0, 0)

// C[M,N] = A[M,K] * B[N,K]^T + bias[N]; A,B bf16 row-major; C bf16 or fp32.
// m97 structure: 128x128 tile, BK=32, mfma_f32_16x16x32_bf16, global_load_lds w16.
template <int OUT_BF16>
__global__ __launch_bounds__(256)
void gemm_bt(const unsigned short* __restrict__ A,
             const unsigned short* __restrict__ B,
             const float* __restrict__ bias,
             void* __restrict__ Cv,
             const int M, const int N, const int K) {
  __shared__ unsigned short As[128 * 32];
  __shared__ unsigned short Bs[128 * 32];
  const int tid  = threadIdx.x;
  const int wave = tid >> 6;
  const int lane = tid & 63;
  const int wm   = (wave & 1) << 6;   // wave's 64-row block
  const int wn   = (wave >> 1) << 6;  // wave's 64-col block
  const int row0 = (int)blockIdx.y << 7;
  const int col0 = (int)blockIdx.x << 7;
  const unsigned short* Ab = A + (size_t)row0 * K;
  const unsigned short* Bb = B + (size_t)col0 * K;
  // staging: lane covers row (lane>>2) of a 16-row group, 16B chunk (lane&3)
  const int srow = wave * 16 + (lane >> 2);
  const int scol = (lane & 3) << 3;
  // fragment addressing: A/B operand layout row=lane&15, k-offset (lane>>4)*8
  const int fr = lane & 15;
  const int fq = (lane >> 4) << 3;
  floatx4 acc[4][4] = {};

  for (int k0 = 0; k0 < K; k0 += 32) {
    __syncthreads();  // previous iter's ds_reads done before overwrite
    GLOAD_LDS16(Ab + (size_t)srow        * K + (k0 + scol), &As[wave * 512]);
    GLOAD_LDS16(Ab + (size_t)(srow + 64) * K + (k0 + scol), &As[2048 + wave * 512]);
    GLOAD_LDS16(Bb + (size_t)srow        * K + (k0 + scol), &Bs[wave * 512]);
    GLOAD_LDS16(Bb + (size_t)(srow + 64) * K + (k0 + scol), &Bs[2048 + wave * 512]);
    __syncthreads();  // drains vmcnt (global_load_lds) before use
    short8 aF[4], bF[4];
#pragma unroll
    for (int i = 0; i < 4; i++) aF[i] = *(const short8*)(&As[(wm + i * 16 + fr) * 32 + fq]);
#pragma unroll
    for (int i = 0; i < 4; i++) bF[i] = *(const short8*)(&Bs[(wn + i * 16 + fr) * 32 + fq]);
#pragma unroll
    for (int mi = 0; mi < 4; mi++)
#pragma unroll
      for (int ni = 0; ni < 4; ni++)
        acc[mi][ni] = __builtin_amdgcn_mfma_f32_16x16x32_bf16(aF[mi], bF[ni], acc[mi][ni], 0, 0, 0);
  }

  // C/D layout: col=lane&15, row=(lane>>4)*4+reg  [m89/m91-verified]
  const int cr = (lane >> 4) << 2;
  const int cn = lane & 15;
  unsigned short* Cb = (unsigned short*)Cv;
  float* Cf = (float*)Cv;
#pragma unroll
  for (int ni = 0; ni < 4; ni++) {
    const int col = col0 + wn + ni * 16 + cn;
    const float bv = bias[col];
#pragma unroll
    for (int mi = 0; mi < 4; mi++) {
      const int rowb = row0 + wm + mi * 16 + cr;
#pragma unroll
      for (int r = 0; r < 4; r++) {
        const float v = acc[mi][ni][r] + bv;
        const size_t idx = (size_t)(rowb + r) * N + col;
        if (OUT_BF16) Cb[idx] = f2bf(v);
        else          Cf[idx] = v;
      }
    }
  }
}

// qkv[B,S,3,H,HD] bf16 -> Q,K,V [B,H,S,HD] bf16; rope on q,k; 1/sqrt(80) folded into Q.
__global__ void rope_kernel(const unsigned short* __restrict__ qkv,
                            unsigned short* __restrict__ Q,
                            unsigned short* __restrict__ K,
                            unsigned short* __restrict__ V) {
  const int idx = blockIdx.x * 256 + threadIdx.x;
  if (idx >= B_ * S_ * H_) return;
  const int h = idx & (H_ - 1);
  const int s = (idx >> 5) & (S_ - 1);
  const int b = idx >> 16;
  const unsigned short* row = qkv + (size_t)(b * S_ + s) * (3 * D_);
  const size_t obase = ((size_t)(b * H_ + h) * S_ + s) * HD_;

  // V: raw bit copy (bf16 identical)
  {
    const uint4* src = (const uint4*)(row + (2 * H_ + h) * HD_);
    uint4* dst = (uint4*)(V + obase);
#pragma unroll
    for (int i = 0; i < 10; i++) dst[i] = src[i];
  }
  // angles: inv_freq = 10000^(-i/16) = exp2(-i*log2(1e4)/16)
  float cc[16], ssn[16];
#pragma unroll
  for (int i = 0; i < 16; i++) {
    const float ang = (float)s * exp2f((float)i * -0.83048202372184059f);
    ssn[i] = sinf(ang);
    cc[i]  = cosf(ang);
  }
  // Q: rope first 32, pass rest; scale ALL dims by 1/sqrt(HD)
  {
    const uint4* src = (const uint4*)(row + h * HD_);
    float f[80], g[80];
#pragma unroll
    for (int i = 0; i < 10; i++) {
      uint4 t = src[i];
      const unsigned short* w = (const unsigned short*)&t;
#pragma unroll
      for (int j = 0; j < 8; j++) f[i * 8 + j] = b2f(w[j]);
    }
#pragma unroll
    for (int i = 0; i < 16; i++) {
      g[i]      = f[i] * cc[i] - f[i + 16] * ssn[i];
      g[i + 16] = f[i] * ssn[i] + f[i + 16] * cc[i];
    }
#pragma unroll
    for (int i = 32; i < 80; i++) g[i] = f[i];
    uint4* dst = (uint4*)(Q + obase);
#pragma unroll
    for (int i = 0; i < 10; i++) {
      uint4 t;
      unsigned short* w = (unsigned short*)&t;
#pragma unroll
      for (int j = 0; j < 8; j++) w[j] = f2bf(g[i * 8 + j] * 0.11180339887498949f);
      dst[i] = t;
    }
  }
  // K: rope first 32, raw-copy tail 48
  {
    const uint4* src = (const uint4*)(row + (H_ + h) * HD_);
    float f[32], g[32];
#pragma unroll
    for (int i = 0; i < 4; i++) {
      uint4 t = src[i];
      const unsigned short* w = (const unsigned short*)&t;
#pragma unroll
      for (int j = 0; j < 8; j++) f[i * 8 + j] = b2f(w[j]);
    }
#pragma unroll
    for (int i = 0; i < 16; i++) {
      g[i]      = f[i] * cc[i] - f[i + 16] * ssn[i];
      g[i + 16] = f[i] * ssn[i] + f[i + 16] * cc[i];
    }
    uint4* dst = (uint4*)(K + obase);
#pragma unroll
    for (int i = 0; i < 4; i++) {
      uint4 t;
      unsigned short* w = (unsigned short*)&t;
#pragma unroll
      for (int j = 0; j < 8; j++) w[j] = f2bf(g[i * 8 + j]);
      dst[i] = t;
    }
#pragma unroll
    for (int i = 4; i < 10; i++) dst[i] = src[i];
  }
}

// Causal flash attention, fp32 math, 32-query x 32-key tiles.
// grid: (S/32, B*H), block 256. Heavy q-tiles first (reversed blockIdx.x).
__global__ __launch_bounds__(256)
void attn_kernel(const unsigned short* __restrict__ Qg,
                 const unsigned short* __restrict__ Kg,
                 const unsigned short* __restrict__ Vg,
                 unsigned short* __restrict__ ctx) {
  __shared__ float Qs[32][81];  // stride 81: conflict-free for per-q reads
  __shared__ float Ks[32][81];
  __shared__ float Vs[32][81];
  __shared__ float Sc[32][33];
  __shared__ float alpha_s[32];
  __shared__ float l_s[32];

  const int tid = threadIdx.x;
  const int bh  = blockIdx.y;
  const int qt  = (int)gridDim.x - 1 - (int)blockIdx.x;
  const int q0  = qt * 32;

  const unsigned short* Qp = Qg + ((size_t)bh * S_ + q0) * HD_;
  const unsigned short* Kp = Kg + (size_t)bh * S_ * HD_;
  const unsigned short* Vp = Vg + (size_t)bh * S_ * HD_;

  for (int i = tid; i < 32 * HD_; i += 256) Qs[i / HD_][i % HD_] = b2f(Qp[i]);

  const int q  = tid & 31;        // query owned for scores & PV
  const int kg = tid >> 5;        // 0..7: key group (scores) / dim group (PV)
  const int d0 = kg * 10;
  float o[10];
#pragma unroll
  for (int j = 0; j < 10; j++) o[j] = 0.f;
  float m_run = -1e30f, l_run = 0.f;  // only meaningful for tid<32

  const int nch = qt + 1;
  for (int c = 0; c < nch; c++) {
    const int k0 = c * 32;
    __syncthreads();
    for (int i = tid; i < 32 * HD_; i += 256) {
      Ks[i / HD_][i % HD_] = b2f(Kp[(size_t)k0 * HD_ + i]);
      Vs[i / HD_][i % HD_] = b2f(Vp[(size_t)k0 * HD_ + i]);
    }
    __syncthreads();
    {
      const int kb = kg * 4;
      float s0 = 0, s1 = 0, s2 = 0, s3 = 0;
      for (int d = 0; d < HD_; d++) {
        const float qd = Qs[q][d];
        s0 = fmaf(qd, Ks[kb + 0][d], s0);
        s1 = fmaf(qd, Ks[kb + 1][d], s1);
        s2 = fmaf(qd, Ks[kb + 2][d], s2);
        s3 = fmaf(qd, Ks[kb + 3][d], s3);
      }
      const int grow = q0 + q;
      if (k0 + kb + 0 > grow) s0 = -1e30f;
      if (k0 + kb + 1 > grow) s1 = -1e30f;
      if (k0 + kb + 2 > grow) s2 = -1e30f;
      if (k0 + kb + 3 > grow) s3 = -1e30f;
      Sc[q][kb + 0] = s0; Sc[q][kb + 1] = s1;
      Sc[q][kb + 2] = s2; Sc[q][kb + 3] = s3;
    }
    __syncthreads();
    if (tid < 32) {
      float mc = m_run;
#pragma unroll
      for (int k = 0; k < 32; k++) mc = fmaxf(mc, Sc[tid][k]);
      const float al = __expf(m_run - mc);
      float ls = 0.f;
#pragma unroll
      for (int k = 0; k < 32; k++) {
        const float p = __expf(Sc[tid][k] - mc);
        Sc[tid][k] = p;
        ls += p;
      }
      l_run = l_run * al + ls;
      m_run = mc;
      alpha_s[tid] = al;
      l_s[tid] = l_run;
    }
    __syncthreads();
    const float al = alpha_s[q];
#pragma unroll
    for (int j = 0; j < 10; j++) o[j] *= al;
#pragma unroll 4
    for (int k = 0; k < 32; k++) {
      const float p = Sc[q][k];
#pragma unroll
      for (int j = 0; j < 10; j++) o[j] = fmaf(p, Vs[k][d0 + j], o[j]);
    }
  }
  const float invl = 1.f / l_s[q];
  const int b = bh >> 5, h = bh & 31;
  unsigned short* op = ctx + ((size_t)(b * S_ + q0 + q) * H_ + h) * HD_ + d0;
#pragma unroll
  for (int j = 0; j < 10; j++) op[j] = f2bf(o[j] * invl);
}

extern "C" void kernel_launch(void* const* d_in, const int* in_sizes, int n_in,
                              void* d_out, int out_size, void* d_ws, size_t ws_size,
                              hipStream_t stream) {
  (void)in_sizes; (void)n_in; (void)out_size; (void)ws_size;
  const float* x      = (const float*)d_in[0];
  const float* wqkv_w = (const float*)d_in[1];
  const float* wqkv_b = (const float*)d_in[2];
  const float* out_w  = (const float*)d_in[3];
  const float* out_b  = (const float*)d_in[4];
  char* ws = (char*)d_ws;

  // workspace layout (bytes); ctx aliases Xb, Wout_bf aliases Wqkv_bf (both dead by then)
  unsigned short* Xb    = (unsigned short*)(ws + 0);          // 4096x2560 bf16 (20.97 MB)
  unsigned short* Wqkvb = (unsigned short*)(ws + 20971520);   // 7680x2560 bf16 (39.32 MB)
  unsigned short* qkv   = (unsigned short*)(ws + 60293120);   // 4096x7680 bf16 (62.91 MB)
  unsigned short* Qb    = (unsigned short*)(ws + 123207680);  // [B,H,S,80] bf16
  unsigned short* Kb    = (unsigned short*)(ws + 144179200);
  unsigned short* Vb    = (unsigned short*)(ws + 165150720);  // end: 186.1 MB
  unsigned short* ctx   = Xb;
  unsigned short* Woutb = Wqkvb;

  cvt_kernel<<<10240, 256, 0, stream>>>(x, Xb, 2621440);
  cvt_kernel<<<19200, 256, 0, stream>>>(wqkv_w, Wqkvb, 4915200);
  gemm_bt<1><<<dim3(60, 32), 256, 0, stream>>>(Xb, Wqkvb, wqkv_b, (void*)qkv, 4096, 7680, 2560);
  rope_kernel<<<512, 256, 0, stream>>>(qkv, Qb, Kb, Vb);
  cvt_kernel<<<6400, 256, 0, stream>>>(out_w, Woutb, 1638400);
  attn_kernel<<<dim3(64, 64), 256, 0, stream>>>(Qb, Kb, Vb, ctx);
  gemm_bt<0><<<dim3(20, 32), 256, 0, stream>>>(ctx, Woutb, out_b, d_out, 4096, 2560, 2560);
}

// Round 2
// 835.239 us; speedup vs baseline: 3.6735x; 3.6735x over previous
//
#include <hip/hip_runtime.h>
#include <cstdint>
#include <cstddef>

#define B_  2
#define S_  2048
#define D_  2560
#define H_  32
#define HD_ 80

typedef __attribute__((ext_vector_type(8))) short  short8;
typedef __attribute__((ext_vector_type(4))) float  floatx4;

__device__ __forceinline__ float b2f(unsigned short u) {
  union { unsigned int i; float f; } x; x.i = ((unsigned int)u) << 16; return x.f;
}
__device__ __forceinline__ unsigned short f2bf(float f) {
  union { float f; unsigned int i; } x; x.f = f;
  unsigned int u = x.i;
  return (unsigned short)((u + 0x7fffu + ((u >> 16) & 1u)) >> 16);
}

// fp32 -> bf16 elementwise, 4 elems/thread (all sizes divisible by 4)
__global__ void cvt_kernel(const float* __restrict__ in, unsigned short* __restrict__ out, int n4) {
  int i = blockIdx.x * 256 + threadIdx.x;
  if (i >= n4) return;
  const float4 v = ((const float4*)in)[i];
  ushort4 r;
  r.x = f2bf(v.x); r.y = f2bf(v.y); r.z = f2bf(v.z); r.w = f2bf(v.w);
  ((ushort4*)out)[i] = r;
}

#define GLOAD_LDS16(g, l)                                                      \
  __builtin_amdgcn_global_load_lds(                                            \
      (const __attribute__((address_space(1))) void*)(g),                      \
      (__attribute__((address_space(3))) void*)(l), 16, 0, 0)

// C[M,N] = A[M,K] * B[N,K]^T + bias[N]; A,B bf16 row-major; C bf16 or fp32.
template <int OUT_BF16>
__global__ __launch_bounds__(256)
void gemm_bt(const unsigned short* __restrict__ A,
             const unsigned short* __restrict__ B,
             const float* __restrict__ bias,
             void* __restrict__ Cv,
             const int M, const int N, const int K) {
  __shared__ unsigned short As[128 * 32];
  __shared__ unsigned short Bs[128 * 32];
  const int tid  = threadIdx.x;
  const int wave = tid >> 6;
  const int lane = tid & 63;
  const int wm   = (wave & 1) << 6;
  const int wn   = (wave >> 1) << 6;
  const int row0 = (int)blockIdx.y << 7;
  const int col0 = (int)blockIdx.x << 7;
  const unsigned short* Ab = A + (size_t)row0 * K;
  const unsigned short* Bb = B + (size_t)col0 * K;
  const int srow = wave * 16 + (lane >> 2);
  const int scol = (lane & 3) << 3;
  const int fr = lane & 15;
  const int fq = (lane >> 4) << 3;
  floatx4 acc[4][4] = {};

  for (int k0 = 0; k0 < K; k0 += 32) {
    __syncthreads();
    GLOAD_LDS16(Ab + (size_t)srow        * K + (k0 + scol), &As[wave * 512]);
    GLOAD_LDS16(Ab + (size_t)(srow + 64) * K + (k0 + scol), &As[2048 + wave * 512]);
    GLOAD_LDS16(Bb + (size_t)srow        * K + (k0 + scol), &Bs[wave * 512]);
    GLOAD_LDS16(Bb + (size_t)(srow + 64) * K + (k0 + scol), &Bs[2048 + wave * 512]);
    __syncthreads();
    short8 aF[4], bF[4];
#pragma unroll
    for (int i = 0; i < 4; i++) aF[i] = *(const short8*)(&As[(wm + i * 16 + fr) * 32 + fq]);
#pragma unroll
    for (int i = 0; i < 4; i++) bF[i] = *(const short8*)(&Bs[(wn + i * 16 + fr) * 32 + fq]);
#pragma unroll
    for (int mi = 0; mi < 4; mi++)
#pragma unroll
      for (int ni = 0; ni < 4; ni++)
        acc[mi][ni] = __builtin_amdgcn_mfma_f32_16x16x32_bf16(aF[mi], bF[ni], acc[mi][ni], 0, 0, 0);
  }

  const int cr = (lane >> 4) << 2;
  const int cn = lane & 15;
  unsigned short* Cb = (unsigned short*)Cv;
  float* Cf = (float*)Cv;
#pragma unroll
  for (int ni = 0; ni < 4; ni++) {
    const int col = col0 + wn + ni * 16 + cn;
    const float bv = bias[col];
#pragma unroll
    for (int mi = 0; mi < 4; mi++) {
      const int rowb = row0 + wm + mi * 16 + cr;
#pragma unroll
      for (int r = 0; r < 4; r++) {
        const float v = acc[mi][ni][r] + bv;
        const size_t idx = (size_t)(rowb + r) * N + col;
        if (OUT_BF16) Cb[idx] = f2bf(v);
        else          Cf[idx] = v;
      }
    }
  }
}

// qkv[B,S,3,H,HD] bf16 -> Q,K [B,H,S,HD] bf16; rope; 1/sqrt(80) folded into Q.
__global__ void rope_kernel(const unsigned short* __restrict__ qkv,
                            unsigned short* __restrict__ Q,
                            unsigned short* __restrict__ K) {
  const int idx = blockIdx.x * 256 + threadIdx.x;
  if (idx >= B_ * S_ * H_) return;
  const int h = idx & (H_ - 1);
  const int s = (idx >> 5) & (S_ - 1);
  const int b = idx >> 16;
  const unsigned short* row = qkv + (size_t)(b * S_ + s) * (3 * D_);
  const size_t obase = ((size_t)(b * H_ + h) * S_ + s) * HD_;

  float cc[16], ssn[16];
#pragma unroll
  for (int i = 0; i < 16; i++) {
    const float ang = (float)s * exp2f((float)i * -0.83048202372184059f);
    ssn[i] = sinf(ang);
    cc[i]  = cosf(ang);
  }
  // Q
  {
    const uint4* src = (const uint4*)(row + h * HD_);
    float f[80], g[80];
#pragma unroll
    for (int i = 0; i < 10; i++) {
      uint4 t = src[i];
      const unsigned short* w = (const unsigned short*)&t;
#pragma unroll
      for (int j = 0; j < 8; j++) f[i * 8 + j] = b2f(w[j]);
    }
#pragma unroll
    for (int i = 0; i < 16; i++) {
      g[i]      = f[i] * cc[i] - f[i + 16] * ssn[i];
      g[i + 16] = f[i] * ssn[i] + f[i + 16] * cc[i];
    }
#pragma unroll
    for (int i = 32; i < 80; i++) g[i] = f[i];
    uint4* dst = (uint4*)(Q + obase);
#pragma unroll
    for (int i = 0; i < 10; i++) {
      uint4 t;
      unsigned short* w = (unsigned short*)&t;
#pragma unroll
      for (int j = 0; j < 8; j++) w[j] = f2bf(g[i * 8 + j] * 0.11180339887498949f);
      dst[i] = t;
    }
  }
  // K
  {
    const uint4* src = (const uint4*)(row + (H_ + h) * HD_);
    float f[32], g[32];
#pragma unroll
    for (int i = 0; i < 4; i++) {
      uint4 t = src[i];
      const unsigned short* w = (const unsigned short*)&t;
#pragma unroll
      for (int j = 0; j < 8; j++) f[i * 8 + j] = b2f(w[j]);
    }
#pragma unroll
    for (int i = 0; i < 16; i++) {
      g[i]      = f[i] * cc[i] - f[i + 16] * ssn[i];
      g[i + 16] = f[i] * ssn[i] + f[i + 16] * cc[i];
    }
    uint4* dst = (uint4*)(K + obase);
#pragma unroll
    for (int i = 0; i < 4; i++) {
      uint4 t;
      unsigned short* w = (unsigned short*)&t;
#pragma unroll
      for (int j = 0; j < 8; j++) w[j] = f2bf(g[i * 8 + j]);
      dst[i] = t;
    }
#pragma unroll
    for (int i = 4; i < 10; i++) dst[i] = src[i];
  }
}

// V slice of qkv[b,s,2,h,:] -> Vt[b,h,d,s]  (64-s-tile LDS transpose per (b,h))
__global__ __launch_bounds__(256)
void vtrans_kernel(const unsigned short* __restrict__ qkv, unsigned short* __restrict__ Vt) {
  __shared__ unsigned short T[64][88];  // [s][d], stride 88 bf16 = 176 B (16B-aligned, bank-rotating)
  const int tid = threadIdx.x;
  const int bh = blockIdx.y;
  const int b = bh >> 5, h = bh & 31;
  const int s0 = (int)blockIdx.x * 64;
  for (int t = tid; t < 640; t += 256) {
    const int r = t / 10, c = t % 10;
    const size_t src = ((size_t)((b * S_ + s0 + r) * 3) + 2) * D_ + h * HD_ + c * 8;
    *(uint4*)&T[r][c * 8] = *(const uint4*)&qkv[src];
  }
  __syncthreads();
  for (int t = tid; t < 640; t += 256) {
    const int d = t / 8, sc = t % 8;
    uint4 o;
    unsigned short* w = (unsigned short*)&o;
#pragma unroll
    for (int j = 0; j < 8; j++) w[j] = T[sc * 8 + j][d];
    *(uint4*)&Vt[((size_t)bh * HD_ + d) * S_ + s0 + sc * 8] = o;
  }
}

// MFMA flash attention. block = 4 waves, 128 queries per (b,h); K-chunks of 64.
// Q,K: [B,H,S,80] bf16 (Q pre-scaled). Vt: [B,H,80,S] bf16. ctx: [B*S, 2560] bf16.
__global__ __launch_bounds__(256)
void attn_mfma(const unsigned short* __restrict__ Qg,
               const unsigned short* __restrict__ Kg,
               const unsigned short* __restrict__ Vtg,
               unsigned short* __restrict__ ctx) {
  __shared__ unsigned short Ks[64 * 104];   // [k][96(+8)], cols 80..95 zero; stride 208B
  __shared__ unsigned short Vs[80 * 72];    // [d][64(+8)]; stride 144B
  __shared__ unsigned short Ps[4][32 * 72]; // per-wave P, [q][64(+8)], XOR-swizzled cols

  const int tid  = threadIdx.x;
  const int wave = tid >> 6;
  const int lane = tid & 63;
  const int fr   = lane & 15;
  const int fg   = lane >> 4;
  const int bh   = blockIdx.y;
  const int qt   = (int)gridDim.x - 1 - (int)blockIdx.x;  // heavy tiles first
  const int q0   = qt << 7;
  const int qbase = q0 + wave * 32;

  const unsigned short* Qrow = Qg  + (size_t)bh * S_ * HD_;
  const unsigned short* Krow = Kg  + (size_t)bh * S_ * HD_;
  const unsigned short* Vrow = Vtg + (size_t)bh * HD_ * S_;

  // Q fragments in registers: rows qbase..qbase+31, K-dim padded 80->96
  short8 qf[2][3];
  const short8 zfrag = {};
#pragma unroll
  for (int mi = 0; mi < 2; mi++)
#pragma unroll
    for (int ks = 0; ks < 3; ks++) {
      const int col = ks * 32 + fg * 8;
      qf[mi][ks] = (col < HD_)
          ? *(const short8*)&Qrow[(size_t)(qbase + mi * 16 + fr) * HD_ + col]
          : zfrag;
    }

  floatx4 accO[2][5] = {};
  float m_run[2][4], l_run[2][4];
#pragma unroll
  for (int mi = 0; mi < 2; mi++)
#pragma unroll
    for (int r = 0; r < 4; r++) { m_run[mi][r] = -1e30f; l_run[mi][r] = 0.f; }

  const int nch = 2 * qt + 2;
  for (int c = 0; c < nch; c++) {
    const int k0 = c * 64;
    __syncthreads();  // previous chunk's LDS reads done
    // stage K tile [64][96], zero-pad cols 80..95
    for (int t = tid; t < 768; t += 256) {
      const int r = t / 12, cc = t % 12;
      uint4 val;
      if (cc < 10) val = *(const uint4*)&Krow[((size_t)(k0 + r)) * HD_ + cc * 8];
      else         val = make_uint4(0, 0, 0, 0);
      *(uint4*)&Ks[r * 104 + cc * 8] = val;
    }
    // stage Vt tile [80][64]
    for (int t = tid; t < 640; t += 256) {
      const int d = t / 8, sc = t % 8;
      *(uint4*)&Vs[d * 72 + sc * 8] =
          *(const uint4*)&Vrow[(size_t)d * S_ + k0 + sc * 8];
    }
    __syncthreads();

    // S = Q K^T  (C layout: row q = fg*4+r, col k = fr)
    floatx4 accS[2][4] = {};
#pragma unroll
    for (int ni = 0; ni < 4; ni++)
#pragma unroll
      for (int ks = 0; ks < 3; ks++) {
        const short8 kf = *(const short8*)&Ks[(ni * 16 + fr) * 104 + ks * 32 + fg * 8];
        accS[0][ni] = __builtin_amdgcn_mfma_f32_16x16x32_bf16(qf[0][ks], kf, accS[0][ni], 0, 0, 0);
        accS[1][ni] = __builtin_amdgcn_mfma_f32_16x16x32_bf16(qf[1][ks], kf, accS[1][ni], 0, 0, 0);
      }

    // causal mask (only on diagonal-crossing chunks for this wave)
    if (k0 + 63 > qbase) {
#pragma unroll
      for (int mi = 0; mi < 2; mi++)
#pragma unroll
        for (int ni = 0; ni < 4; ni++)
#pragma unroll
          for (int r = 0; r < 4; r++) {
            const int qg = qbase + mi * 16 + fg * 4 + r;
            const int kg = k0 + ni * 16 + fr;
            if (kg > qg) accS[mi][ni][r] = -1e30f;
          }
    }

    // online softmax; write P to per-wave LDS (A-layout source), swizzled col^(fg<<3)
#pragma unroll
    for (int mi = 0; mi < 2; mi++) {
      float mx[4], al[4], sm[4];
#pragma unroll
      for (int r = 0; r < 4; r++) {
        float v = fmaxf(fmaxf(accS[mi][0][r], accS[mi][1][r]),
                        fmaxf(accS[mi][2][r], accS[mi][3][r]));
        v = fmaxf(v, __shfl_xor(v, 1));
        v = fmaxf(v, __shfl_xor(v, 2));
        v = fmaxf(v, __shfl_xor(v, 4));
        v = fmaxf(v, __shfl_xor(v, 8));
        mx[r] = fmaxf(m_run[mi][r], v);
        al[r] = __expf(m_run[mi][r] - mx[r]);
        m_run[mi][r] = mx[r];
        sm[r] = 0.f;
      }
#pragma unroll
      for (int ni = 0; ni < 4; ni++)
#pragma unroll
        for (int r = 0; r < 4; r++) {
          const float p = __expf(accS[mi][ni][r] - mx[r]);
          sm[r] += p;
          const int prow = mi * 16 + fg * 4 + r;
          const int pcol = (ni * 16 + fr) ^ (fg << 3);  // swizzle: key = (prow>>2)&3 == fg
          Ps[wave][prow * 72 + pcol] = f2bf(p);
        }
#pragma unroll
      for (int r = 0; r < 4; r++) {
        float s = sm[r];
        s += __shfl_xor(s, 1);
        s += __shfl_xor(s, 2);
        s += __shfl_xor(s, 4);
        s += __shfl_xor(s, 8);
        l_run[mi][r] = l_run[mi][r] * al[r] + s;
      }
#pragma unroll
      for (int dt = 0; dt < 5; dt++)
#pragma unroll
        for (int r = 0; r < 4; r++) accO[mi][dt][r] *= al[r];
    }

    // O += P V   (A = P rows q, B = Vt rows d; wave-local P, compiler inserts lgkmcnt)
#pragma unroll
    for (int kstep = 0; kstep < 2; kstep++) {
      short8 pf[2];
#pragma unroll
      for (int mi = 0; mi < 2; mi++) {
        const int prow = mi * 16 + fr;
        const int pcol = (kstep * 32 + fg * 8) ^ ((fr >> 2) << 3);  // unswizzle key = (prow>>2)&3
        pf[mi] = *(const short8*)&Ps[wave][prow * 72 + pcol];
      }
#pragma unroll
      for (int dt = 0; dt < 5; dt++) {
        const short8 vf = *(const short8*)&Vs[(dt * 16 + fr) * 72 + kstep * 32 + fg * 8];
        accO[0][dt] = __builtin_amdgcn_mfma_f32_16x16x32_bf16(pf[0], vf, accO[0][dt], 0, 0, 0);
        accO[1][dt] = __builtin_amdgcn_mfma_f32_16x16x32_bf16(pf[1], vf, accO[1][dt], 0, 0, 0);
      }
    }
  }

  // epilogue: ctx[b*S+q][h*80+d] = O / l
  const int b = bh >> 5, h = bh & 31;
#pragma unroll
  for (int mi = 0; mi < 2; mi++) {
    float inv[4];
#pragma unroll
    for (int r = 0; r < 4; r++) inv[r] = 1.f / l_run[mi][r];
#pragma unroll
    for (int dt = 0; dt < 5; dt++) {
      const int d = dt * 16 + fr;
#pragma unroll
      for (int r = 0; r < 4; r++) {
        const int q = qbase + mi * 16 + fg * 4 + r;
        ctx[(size_t)(b * S_ + q) * D_ + h * HD_ + d] = f2bf(accO[mi][dt][r] * inv[r]);
      }
    }
  }
}

extern "C" void kernel_launch(void* const* d_in, const int* in_sizes, int n_in,
                              void* d_out, int out_size, void* d_ws, size_t ws_size,
                              hipStream_t stream) {
  (void)in_sizes; (void)n_in; (void)out_size; (void)ws_size;
  const float* x      = (const float*)d_in[0];
  const float* wqkv_w = (const float*)d_in[1];
  const float* wqkv_b = (const float*)d_in[2];
  const float* out_w  = (const float*)d_in[3];
  const float* out_b  = (const float*)d_in[4];
  char* ws = (char*)d_ws;

  unsigned short* Xb    = (unsigned short*)(ws + 0);          // 4096x2560 bf16
  unsigned short* Wqkvb = (unsigned short*)(ws + 20971520);   // 7680x2560 bf16
  unsigned short* qkv   = (unsigned short*)(ws + 60293120);   // 4096x7680 bf16
  unsigned short* Qb    = (unsigned short*)(ws + 123207680);  // [B,H,S,80] bf16
  unsigned short* Kb    = (unsigned short*)(ws + 144179200);  // [B,H,S,80] bf16
  unsigned short* Vtg   = (unsigned short*)(ws + 165150720);  // [B,H,80,S] bf16; end 186.1 MB
  unsigned short* ctx   = Xb;     // Xb dead after QKV gemm
  unsigned short* Woutb = Wqkvb;  // Wqkvb dead after QKV gemm

  cvt_kernel<<<10240, 256, 0, stream>>>(x, Xb, 2621440);
  cvt_kernel<<<19200, 256, 0, stream>>>(wqkv_w, Wqkvb, 4915200);
  gemm_bt<1><<<dim3(60, 32), 256, 0, stream>>>(Xb, Wqkvb, wqkv_b, (void*)qkv, 4096, 7680, 2560);
  rope_kernel<<<512, 256, 0, stream>>>(qkv, Qb, Kb);
  vtrans_kernel<<<dim3(32, 64), 256, 0, stream>>>(qkv, Vtg);
  cvt_kernel<<<6400, 256, 0, stream>>>(out_w, Woutb, 1638400);
  attn_mfma<<<dim3(16, 64), 256, 0, stream>>>(Qb, Kb, Vtg, ctx);
  gemm_bt<0><<<dim3(20, 32), 256, 0, stream>>>(ctx, Woutb, out_b, d_out, 4096, 2560, 2560);
}

// Round 3
// 673.990 us; speedup vs baseline: 4.5524x; 1.2392x over previous
//
#include <hip/hip_runtime.h>
#include <cstdint>
#include <cstddef>

#define B_  2
#define S_  2048
#define D_  2560
#define H_  32
#define HD_ 80

typedef __attribute__((ext_vector_type(8))) short  short8;
typedef __attribute__((ext_vector_type(4))) float  floatx4;

__device__ __forceinline__ float b2f(unsigned short u) {
  union { unsigned int i; float f; } x; x.i = ((unsigned int)u) << 16; return x.f;
}
__device__ __forceinline__ unsigned short f2bf(float f) {
  union { float f; unsigned int i; } x; x.f = f;
  unsigned int u = x.i;
  return (unsigned short)((u + 0x7fffu + ((u >> 16) & 1u)) >> 16);
}

// fp32 -> bf16 elementwise, 4 elems/thread
__global__ void cvt_kernel(const float* __restrict__ in, unsigned short* __restrict__ out, int n4) {
  int i = blockIdx.x * 256 + threadIdx.x;
  if (i >= n4) return;
  const float4 v = ((const float4*)in)[i];
  ushort4 r;
  r.x = f2bf(v.x); r.y = f2bf(v.y); r.z = f2bf(v.z); r.w = f2bf(v.w);
  ((ushort4*)out)[i] = r;
}

#define GLOAD_LDS16(g, l)                                                      \
  __builtin_amdgcn_global_load_lds(                                            \
      (const __attribute__((address_space(1))) void*)(g),                      \
      (__attribute__((address_space(3))) void*)(l), 16, 0, 0)

// C[M,N] = A[M,K] * B[N,K]^T + bias[N]; A,B bf16 row-major; C bf16 or fp32.
template <int OUT_BF16>
__global__ __launch_bounds__(256)
void gemm_bt(const unsigned short* __restrict__ A,
             const unsigned short* __restrict__ B,
             const float* __restrict__ bias,
             void* __restrict__ Cv,
             const int M, const int N, const int K) {
  __shared__ unsigned short As[128 * 32];
  __shared__ unsigned short Bs[128 * 32];
  const int tid  = threadIdx.x;
  const int wave = tid >> 6;
  const int lane = tid & 63;
  const int wm   = (wave & 1) << 6;
  const int wn   = (wave >> 1) << 6;
  const int row0 = (int)blockIdx.y << 7;
  const int col0 = (int)blockIdx.x << 7;
  const unsigned short* Ab = A + (size_t)row0 * K;
  const unsigned short* Bb = B + (size_t)col0 * K;
  const int srow = wave * 16 + (lane >> 2);
  const int scol = (lane & 3) << 3;
  const int fr = lane & 15;
  const int fq = (lane >> 4) << 3;
  floatx4 acc[4][4] = {};

  for (int k0 = 0; k0 < K; k0 += 32) {
    __syncthreads();
    GLOAD_LDS16(Ab + (size_t)srow        * K + (k0 + scol), &As[wave * 512]);
    GLOAD_LDS16(Ab + (size_t)(srow + 64) * K + (k0 + scol), &As[2048 + wave * 512]);
    GLOAD_LDS16(Bb + (size_t)srow        * K + (k0 + scol), &Bs[wave * 512]);
    GLOAD_LDS16(Bb + (size_t)(srow + 64) * K + (k0 + scol), &Bs[2048 + wave * 512]);
    __syncthreads();
    short8 aF[4], bF[4];
#pragma unroll
    for (int i = 0; i < 4; i++) aF[i] = *(const short8*)(&As[(wm + i * 16 + fr) * 32 + fq]);
#pragma unroll
    for (int i = 0; i < 4; i++) bF[i] = *(const short8*)(&Bs[(wn + i * 16 + fr) * 32 + fq]);
#pragma unroll
    for (int mi = 0; mi < 4; mi++)
#pragma unroll
      for (int ni = 0; ni < 4; ni++)
        acc[mi][ni] = __builtin_amdgcn_mfma_f32_16x16x32_bf16(aF[mi], bF[ni], acc[mi][ni], 0, 0, 0);
  }

  const int cr = (lane >> 4) << 2;
  const int cn = lane & 15;
  unsigned short* Cb = (unsigned short*)Cv;
  float* Cf = (float*)Cv;
#pragma unroll
  for (int ni = 0; ni < 4; ni++) {
    const int col = col0 + wn + ni * 16 + cn;
    const float bv = bias[col];
#pragma unroll
    for (int mi = 0; mi < 4; mi++) {
      const int rowb = row0 + wm + mi * 16 + cr;
#pragma unroll
      for (int r = 0; r < 4; r++) {
        const float v = acc[mi][ni][r] + bv;
        const size_t idx = (size_t)(rowb + r) * N + col;
        if (OUT_BF16) Cb[idx] = f2bf(v);
        else          Cf[idx] = v;
      }
    }
  }
}

// qkv[B,S,3,H,HD] bf16 -> Q,K [B,H,S,HD] bf16; rope; Q scaled by (1/sqrt(80))*log2(e).
__global__ void rope_kernel(const unsigned short* __restrict__ qkv,
                            unsigned short* __restrict__ Q,
                            unsigned short* __restrict__ K) {
  const int idx = blockIdx.x * 256 + threadIdx.x;
  if (idx >= B_ * S_ * H_) return;
  const int h = idx & (H_ - 1);
  const int s = (idx >> 5) & (S_ - 1);
  const int b = idx >> 16;
  const unsigned short* row = qkv + (size_t)(b * S_ + s) * (3 * D_);
  const size_t obase = ((size_t)(b * H_ + h) * S_ + s) * HD_;

  float cc[16], ssn[16];
#pragma unroll
  for (int i = 0; i < 16; i++) {
    const float ang = (float)s * exp2f((float)i * -0.83048202372184059f);
    ssn[i] = sinf(ang);
    cc[i]  = cosf(ang);
  }
  // Q (scale includes log2(e) for fixed-max exp2 softmax)
  {
    const float QS = 0.11180339887498949f * 1.4426950408889634f;
    const uint4* src = (const uint4*)(row + h * HD_);
    float f[80], g[80];
#pragma unroll
    for (int i = 0; i < 10; i++) {
      uint4 t = src[i];
      const unsigned short* w = (const unsigned short*)&t;
#pragma unroll
      for (int j = 0; j < 8; j++) f[i * 8 + j] = b2f(w[j]);
    }
#pragma unroll
    for (int i = 0; i < 16; i++) {
      g[i]      = f[i] * cc[i] - f[i + 16] * ssn[i];
      g[i + 16] = f[i] * ssn[i] + f[i + 16] * cc[i];
    }
#pragma unroll
    for (int i = 32; i < 80; i++) g[i] = f[i];
    uint4* dst = (uint4*)(Q + obase);
#pragma unroll
    for (int i = 0; i < 10; i++) {
      uint4 t;
      unsigned short* w = (unsigned short*)&t;
#pragma unroll
      for (int j = 0; j < 8; j++) w[j] = f2bf(g[i * 8 + j] * QS);
      dst[i] = t;
    }
  }
  // K
  {
    const uint4* src = (const uint4*)(row + (H_ + h) * HD_);
    float f[32], g[32];
#pragma unroll
    for (int i = 0; i < 4; i++) {
      uint4 t = src[i];
      const unsigned short* w = (const unsigned short*)&t;
#pragma unroll
      for (int j = 0; j < 8; j++) f[i * 8 + j] = b2f(w[j]);
    }
#pragma unroll
    for (int i = 0; i < 16; i++) {
      g[i]      = f[i] * cc[i] - f[i + 16] * ssn[i];
      g[i + 16] = f[i] * ssn[i] + f[i + 16] * cc[i];
    }
    uint4* dst = (uint4*)(K + obase);
#pragma unroll
    for (int i = 0; i < 4; i++) {
      uint4 t;
      unsigned short* w = (unsigned short*)&t;
#pragma unroll
      for (int j = 0; j < 8; j++) w[j] = f2bf(g[i * 8 + j]);
      dst[i] = t;
    }
#pragma unroll
    for (int i = 4; i < 10; i++) dst[i] = src[i];
  }
}

// V slice of qkv -> contiguous padded tiles Vtile[bh][s-chunk64][80][72]
// (tile format == attn's Vs LDS layout, so staging is a flat DMA copy)
__global__ __launch_bounds__(256)
void vtrans_kernel(const unsigned short* __restrict__ qkv, unsigned short* __restrict__ Vt) {
  __shared__ unsigned short T[64][88];
  const int tid = threadIdx.x;
  const int bh = blockIdx.y;
  const int b = bh >> 5, h = bh & 31;
  const int tile = blockIdx.x;
  const int s0 = tile * 64;
  for (int t = tid; t < 640; t += 256) {
    const int r = t / 10, c = t % 10;
    const size_t src = ((size_t)((b * S_ + s0 + r) * 3) + 2) * D_ + h * HD_ + c * 8;
    *(uint4*)&T[r][c * 8] = *(const uint4*)&qkv[src];
  }
  __syncthreads();
  unsigned short* tb = Vt + ((size_t)bh * 32 + tile) * (80 * 72);
  for (int t = tid; t < 640; t += 256) {
    const int d = t / 8, sc = t % 8;
    uint4 o;
    unsigned short* w = (unsigned short*)&o;
#pragma unroll
    for (int j = 0; j < 8; j++) w[j] = T[sc * 8 + j][d];
    *(uint4*)&tb[d * 72 + sc * 8] = o;
  }
}

// MFMA flash attention, fixed-max exp2 softmax, async DMA staging.
// block = 4 waves, 128 queries per (b,h); K-chunks of 64.
__global__ __launch_bounds__(256, 4)
void attn_mfma(const unsigned short* __restrict__ Qg,
               const unsigned short* __restrict__ Kg,
               const unsigned short* __restrict__ Vtg,
               unsigned short* __restrict__ ctx) {
  __shared__ unsigned short Ks[64 * 80];    // [k][80], stride 160 B (= global row: DMA-contiguous)
  __shared__ unsigned short Vs[80 * 72];    // [d][64+8], = Vtile format (DMA-contiguous)
  __shared__ unsigned short Ps[4][32 * 72]; // per-wave P, [q][64+8], XOR-swizzled cols

  const int tid  = threadIdx.x;
  const int wave = tid >> 6;
  const int lane = tid & 63;
  const int fr   = lane & 15;
  const int fg   = lane >> 4;
  const int bh   = blockIdx.y;
  const int qt   = (int)gridDim.x - 1 - (int)blockIdx.x;  // heavy tiles first
  const int qbase = (qt << 7) + wave * 32;

  const unsigned short* Qrow  = Qg  + (size_t)bh * S_ * HD_;
  const unsigned short* Krow  = Kg  + (size_t)bh * S_ * HD_;
  const unsigned short* Vtile = Vtg + (size_t)bh * 32 * (80 * 72);

  // Q fragments in registers; 3rd K-step fragment zeroed for fg>=2 (covers cols 80..95)
  short8 qf[2][3];
  const short8 zfrag = {};
#pragma unroll
  for (int mi = 0; mi < 2; mi++) {
    const unsigned short* qp = Qrow + (size_t)(qbase + mi * 16 + fr) * HD_;
    qf[mi][0] = *(const short8*)&qp[fg * 8];
    qf[mi][1] = *(const short8*)&qp[32 + fg * 8];
    qf[mi][2] = (fg < 2) ? *(const short8*)&qp[64 + fg * 8] : zfrag;
  }

  floatx4 accO[2][5] = {};
  float l_part[2][4] = {};

  const int nch = 2 * qt + 2;
  for (int c = 0; c < nch; c++) {
    const int k0 = c * 64;
    __syncthreads();  // previous chunk's LDS reads done
    // K tile: contiguous 10240-B DMA (10 x 1024 B)
    {
      const unsigned short* Kt = Krow + (size_t)k0 * HD_;
      for (int i = wave; i < 10; i += 4)
        GLOAD_LDS16(Kt + i * 512 + lane * 8, &Ks[i * 512]);
    }
    // V tile: contiguous 11520-B DMA (11 x 1024 B + 1 overlapped tail)
    {
      const unsigned short* Vt = Vtile + (size_t)c * (80 * 72);
      for (int i = wave; i < 12; i += 4) {
        const int off = (i < 11) ? i * 512 : 5248;
        GLOAD_LDS16(Vt + off + lane * 8, &Vs[off]);
      }
    }
    __syncthreads();  // drains DMA vmcnt

    // S' = (Q*scale*log2e) K^T   (C layout: row q = fg*4+r, col k = fr)
    floatx4 accS[2][4] = {};
#pragma unroll
    for (int ni = 0; ni < 4; ni++) {
      const unsigned short* kp = &Ks[(ni * 16 + fr) * 80];
      const short8 kf0 = *(const short8*)&kp[fg * 8];
      const short8 kf1 = *(const short8*)&kp[32 + fg * 8];
      const short8 kf2 = *(const short8*)&kp[64 + (fg & 1) * 8];  // fg>=2 lanes: A-side is zero
      accS[0][ni] = __builtin_amdgcn_mfma_f32_16x16x32_bf16(qf[0][0], kf0, accS[0][ni], 0, 0, 0);
      accS[1][ni] = __builtin_amdgcn_mfma_f32_16x16x32_bf16(qf[1][0], kf0, accS[1][ni], 0, 0, 0);
      accS[0][ni] = __builtin_amdgcn_mfma_f32_16x16x32_bf16(qf[0][1], kf1, accS[0][ni], 0, 0, 0);
      accS[1][ni] = __builtin_amdgcn_mfma_f32_16x16x32_bf16(qf[1][1], kf1, accS[1][ni], 0, 0, 0);
      accS[0][ni] = __builtin_amdgcn_mfma_f32_16x16x32_bf16(qf[0][2], kf2, accS[0][ni], 0, 0, 0);
      accS[1][ni] = __builtin_amdgcn_mfma_f32_16x16x32_bf16(qf[1][2], kf2, accS[1][ni], 0, 0, 0);
    }

    // causal mask (diagonal-crossing chunks only)
    if (k0 + 63 > qbase) {
#pragma unroll
      for (int mi = 0; mi < 2; mi++)
#pragma unroll
        for (int ni = 0; ni < 4; ni++)
#pragma unroll
          for (int r = 0; r < 4; r++) {
            const int qg = qbase + mi * 16 + fg * 4 + r;
            const int kg = k0 + ni * 16 + fr;
            if (kg > qg) accS[mi][ni][r] = -1e30f;
          }
    }

    // fixed-max softmax: p = exp2(S'); per-lane l partials; P -> LDS (swizzled)
#pragma unroll
    for (int mi = 0; mi < 2; mi++)
#pragma unroll
      for (int ni = 0; ni < 4; ni++)
#pragma unroll
        for (int r = 0; r < 4; r++) {
          const float p = __builtin_amdgcn_exp2f(accS[mi][ni][r]);
          l_part[mi][r] += p;
          const int prow = mi * 16 + fg * 4 + r;
          const int pcol = (ni * 16 + fr) ^ (fg << 3);
          Ps[wave][prow * 72 + pcol] = f2bf(p);
        }

    // O += P V (wave-local P round-trip; compiler inserts lgkmcnt)
#pragma unroll
    for (int kstep = 0; kstep < 2; kstep++) {
      short8 pf[2];
#pragma unroll
      for (int mi = 0; mi < 2; mi++) {
        const int prow = mi * 16 + fr;
        const int pcol = (kstep * 32 + fg * 8) ^ ((fr >> 2) << 3);
        pf[mi] = *(const short8*)&Ps[wave][prow * 72 + pcol];
      }
#pragma unroll
      for (int dt = 0; dt < 5; dt++) {
        const short8 vf = *(const short8*)&Vs[(dt * 16 + fr) * 72 + kstep * 32 + fg * 8];
        accO[0][dt] = __builtin_amdgcn_mfma_f32_16x16x32_bf16(pf[0], vf, accO[0][dt], 0, 0, 0);
        accO[1][dt] = __builtin_amdgcn_mfma_f32_16x16x32_bf16(pf[1], vf, accO[1][dt], 0, 0, 0);
      }
    }
  }

  // epilogue: reduce l across the 16 col-lanes once; ctx[b*S+q][h*80+d] = O / l
  const int b = bh >> 5, h = bh & 31;
#pragma unroll
  for (int mi = 0; mi < 2; mi++) {
    float inv[4];
#pragma unroll
    for (int r = 0; r < 4; r++) {
      float s = l_part[mi][r];
      s += __shfl_xor(s, 1);
      s += __shfl_xor(s, 2);
      s += __shfl_xor(s, 4);
      s += __shfl_xor(s, 8);
      inv[r] = 1.f / s;
    }
#pragma unroll
    for (int dt = 0; dt < 5; dt++) {
      const int d = dt * 16 + fr;
#pragma unroll
      for (int r = 0; r < 4; r++) {
        const int q = qbase + mi * 16 + fg * 4 + r;
        ctx[(size_t)(b * S_ + q) * D_ + h * HD_ + d] = f2bf(accO[mi][dt][r] * inv[r]);
      }
    }
  }
}

extern "C" void kernel_launch(void* const* d_in, const int* in_sizes, int n_in,
                              void* d_out, int out_size, void* d_ws, size_t ws_size,
                              hipStream_t stream) {
  (void)in_sizes; (void)n_in; (void)out_size; (void)ws_size;
  const float* x      = (const float*)d_in[0];
  const float* wqkv_w = (const float*)d_in[1];
  const float* wqkv_b = (const float*)d_in[2];
  const float* out_w  = (const float*)d_in[3];
  const float* out_b  = (const float*)d_in[4];
  char* ws = (char*)d_ws;

  unsigned short* Xb    = (unsigned short*)(ws + 0);          // 4096x2560 bf16
  unsigned short* Wqkvb = (unsigned short*)(ws + 20971520);   // 7680x2560 bf16 (dead after gemm1)
  unsigned short* qkv   = (unsigned short*)(ws + 60293120);   // 4096x7680 bf16
  unsigned short* Qb    = (unsigned short*)(ws + 123207680);  // [B,H,S,80] bf16
  unsigned short* Kb    = (unsigned short*)(ws + 144179200);  // [B,H,S,80] bf16; end 165.2 MB
  unsigned short* ctx   = Xb;                                 // Xb dead after gemm1
  unsigned short* Woutb = Wqkvb;                              // first 13.1 MB of Wqkvb slot
  unsigned short* Vtile = (unsigned short*)(ws + 34078720);   // 23.6 MB inside dead Wqkvb tail

  cvt_kernel<<<10240, 256, 0, stream>>>(x, Xb, 2621440);
  cvt_kernel<<<19200, 256, 0, stream>>>(wqkv_w, Wqkvb, 4915200);
  gemm_bt<1><<<dim3(60, 32), 256, 0, stream>>>(Xb, Wqkvb, wqkv_b, (void*)qkv, 4096, 7680, 2560);
  rope_kernel<<<512, 256, 0, stream>>>(qkv, Qb, Kb);
  vtrans_kernel<<<dim3(32, 64), 256, 0, stream>>>(qkv, Vtile);
  cvt_kernel<<<6400, 256, 0, stream>>>(out_w, Woutb, 1638400);
  attn_mfma<<<dim3(16, 64), 256, 0, stream>>>(Qb, Kb, Vtile, ctx);
  gemm_bt<0><<<dim3(20, 32), 256, 0, stream>>>(ctx, Woutb, out_b, d_out, 4096, 2560, 2560);
}